// Round 17
// baseline (310.736 us; speedup 1.0000x reference)
//
#include <hip/hip_runtime.h>
#include <stdint.h>

#define NHID 128
#define EPB 64          // edges per classifier tile
#define RP  296         // padded repr row (f16): 592B stride, 16B-aligned
#define Z1P 136         // padded z1 row (f16): 272B stride, 16B-aligned
#define Z2P 72          // padded z2 row (f16): 144B stride, 16B-aligned

typedef _Float16 half8 __attribute__((ext_vector_type(8)));
typedef _Float16 half4v __attribute__((ext_vector_type(4)));
typedef float f32x4 __attribute__((ext_vector_type(4)));

// ---------------- zero (16B granularity) ----------------
__global__ void zero_kernel(float* __restrict__ p, size_t n4) {
    size_t i = (size_t)blockIdx.x * blockDim.x + threadIdx.x;
    size_t stride = (size_t)gridDim.x * blockDim.x;
    float4* p4 = (float4*)p;
    float4 z = make_float4(0.f, 0.f, 0.f, 0.f);
    for (size_t j = i; j < n4; j += stride) p4[j] = z;
}

// ---------------- fp32 -> f16 cast (8 elems/thread) ----------------
__global__ void cast_f32_f16(const float* __restrict__ in, _Float16* __restrict__ outp,
                             int n8) {
    int i = blockIdx.x * 256 + threadIdx.x;
    int stride = gridDim.x * 256;
    for (int j = i; j < n8; j += stride) {
        float4 a = ((const float4*)in)[2 * j];
        float4 b = ((const float4*)in)[2 * j + 1];
        half8 v;
        v[0] = (_Float16)a.x; v[1] = (_Float16)a.y; v[2] = (_Float16)a.z; v[3] = (_Float16)a.w;
        v[4] = (_Float16)b.x; v[5] = (_Float16)b.y; v[6] = (_Float16)b.z; v[7] = (_Float16)b.w;
        ((half8*)outp)[j] = v;
    }
}

// ---------------- weight prep: fp32 -> f16, transposed ----------------
__global__ void prep_weights(const float* __restrict__ Wc1, const float* __restrict__ Wc2,
                             const float* __restrict__ Wc3,
                             const float* __restrict__ W1l, const float* __restrict__ W1r,
                             const float* __restrict__ W2l, const float* __restrict__ W2r,
                             _Float16* __restrict__ W1T, _Float16* __restrict__ W2T,
                             _Float16* __restrict__ W3T,
                             _Float16* __restrict__ WT1, _Float16* __restrict__ WT2) {
    int tid = blockIdx.x * 256 + threadIdx.x;
    if (tid < 288 * 128) {
        int n = tid / 288, k = tid % 288;
        W1T[tid] = (_Float16)Wc1[(size_t)k * 128 + n];
    }
    if (tid < 64 * 128) {
        int n = tid / 128, k = tid % 128;
        W2T[tid] = (_Float16)Wc2[(size_t)k * 64 + n];
    }
    if (tid < 16 * 64) {
        int n = tid / 64, k = tid % 64;
        W3T[tid] = (n < 3) ? (_Float16)Wc3[(size_t)k * 3 + n] : (_Float16)0.f;
    }
    if (tid < 128 * 256) {
        int n = tid / 256, k = tid % 256;
        WT1[tid] = (k < 128) ? (_Float16)W1l[(size_t)k * 128 + n]
                             : (_Float16)W1r[(size_t)(k - 128) * 128 + n];
        WT2[tid] = (k < 128) ? (_Float16)W2l[(size_t)k * 128 + n]
                             : (_Float16)W2r[(size_t)(k - 128) * 128 + n];
    }
}

// ---------------- CSR build ----------------
__global__ void count_kernel(const int* __restrict__ dst, int* __restrict__ deg, int E) {
    int e = blockIdx.x * 256 + threadIdx.x;
    if (e < E) atomicAdd(&deg[dst[e]], 1);
}

__global__ __launch_bounds__(256) void csr_reduce(const int* __restrict__ deg,
                                                  int* __restrict__ bsum, int N) {
    __shared__ int b[256];
    int t = threadIdx.x;
    int i = blockIdx.x * 256 + t;
    int v = (i < N) ? deg[i] : 0;
    b[t] = v;
    __syncthreads();
#pragma unroll
    for (int off = 128; off > 0; off >>= 1) {
        if (t < off) b[t] += b[t + off];
        __syncthreads();
    }
    if (t == 0) bsum[blockIdx.x] = b[0];
}

__global__ __launch_bounds__(256) void csr_scan_partials(const int* __restrict__ bsum,
                                                         int* __restrict__ bpre,
                                                         int* __restrict__ rowptr,
                                                         int nb, int N) {
    __shared__ int b[256];
    int t = threadIdx.x;
    int v = (t < nb) ? bsum[t] : 0;
    b[t] = v;
    __syncthreads();
    int x = v;
#pragma unroll
    for (int off = 1; off < 256; off <<= 1) {
        int y = (t >= off) ? b[t - off] : 0;
        __syncthreads();
        x += y;
        b[t] = x;
        __syncthreads();
    }
    if (t < nb) bpre[t] = x - v;           // exclusive
    if (t == nb - 1) rowptr[N] = x;        // total
}

__global__ __launch_bounds__(256) void csr_emit(const int* __restrict__ deg,
                                                const int* __restrict__ bpre,
                                                int* __restrict__ rowptr,
                                                int* __restrict__ cursor, int N) {
    __shared__ int b[256];
    int t = threadIdx.x;
    int i = blockIdx.x * 256 + t;
    int v = (i < N) ? deg[i] : 0;
    b[t] = v;
    __syncthreads();
    int x = v;
#pragma unroll
    for (int off = 1; off < 256; off <<= 1) {
        int y = (t >= off) ? b[t - off] : 0;
        __syncthreads();
        x += y;
        b[t] = x;
        __syncthreads();
    }
    if (i < N) {
        int excl = bpre[blockIdx.x] + x - v;
        rowptr[i] = excl;
        cursor[i] = excl;
    }
}

// fill: CSR adjacency + edge permutation (eperm[p] = original edge id)
__global__ void fill_kernel(const int* __restrict__ src, const int* __restrict__ dst,
                            int* __restrict__ cursor, int* __restrict__ ssrc,
                            int* __restrict__ eperm, int E) {
    int e = blockIdx.x * 256 + threadIdx.x;
    if (e < E) {
        int p = atomicAdd(&cursor[dst[e]], 1);
        ssrc[p] = src[e];
        eperm[p] = e;
    }
}

// ---------------- fused pull-aggregate + SAGE (MFMA) + BN + ReLU ----------------
// r15 proven body: 512 threads, 16 nodes/block; 2 teams x 16 lanes per node.
__global__ __launch_bounds__(512) void sage_layer(
    const _Float16* __restrict__ xin, const int* __restrict__ rowptr,
    const int* __restrict__ ssrc,
    const _Float16* __restrict__ WT, const float* __restrict__ bl,
    const float* __restrict__ gam, const float* __restrict__ bet,
    const float* __restrict__ mu, const float* __restrict__ var,
    _Float16* __restrict__ outp, int N) {
    __shared__ _Float16 sAX[16][264];   // [0:128)=agg, [128:256)=x
    int tid = threadIdx.x;
    int node0 = blockIdx.x * 16;

    { // ---- gather phase
        int i = tid >> 5;              // node slot 0..15
        int lsub = tid & 31;
        int q16 = lsub & 15;           // feature octet (8 halfs = 16B)
        int team = lsub >> 4;          // 0 or 1
        int node = node0 + i;
        int rs = rowptr[node], re = rowptr[node + 1];
        float acc[8];
#pragma unroll
        for (int c = 0; c < 8; c++) acc[c] = 0.f;
        int e = rs + team;
        for (; e + 6 < re; e += 8) {   // edges e, e+2, e+4, e+6 (this team)
            int s0 = ssrc[e], s1 = ssrc[e + 2], s2 = ssrc[e + 4], s3 = ssrc[e + 6];
            half8 v0 = *(const half8*)&xin[(size_t)s0 * NHID + q16 * 8];
            half8 v1 = *(const half8*)&xin[(size_t)s1 * NHID + q16 * 8];
            half8 v2 = *(const half8*)&xin[(size_t)s2 * NHID + q16 * 8];
            half8 v3 = *(const half8*)&xin[(size_t)s3 * NHID + q16 * 8];
#pragma unroll
            for (int c = 0; c < 8; c++)
                acc[c] += ((float)v0[c] + (float)v1[c]) + ((float)v2[c] + (float)v3[c]);
        }
        for (; e < re; e += 2) {
            half8 v = *(const half8*)&xin[(size_t)ssrc[e] * NHID + q16 * 8];
#pragma unroll
            for (int c = 0; c < 8; c++) acc[c] += (float)v[c];
        }
#pragma unroll
        for (int c = 0; c < 8; c++) acc[c] += __shfl_xor(acc[c], 16);
        int deg = re - rs;
        float inv = (deg > 0) ? (1.0f / (float)deg) : 0.f;
        if (team == 0) {
            half8 av;
#pragma unroll
            for (int c = 0; c < 8; c++) av[c] = (_Float16)(acc[c] * inv);
            *(half8*)&sAX[i][q16 * 8] = av;
            *(half8*)&sAX[i][128 + q16 * 8] =
                *(const half8*)&xin[(size_t)node * NHID + q16 * 8];
        }
    }
    __syncthreads();

    // ---- MFMA GEMM: wave = ntile
    {
        int lane = tid & 63;
        int wave = tid >> 6;          // 0..7
        int l15 = lane & 15;
        int g = lane >> 4;
        const _Float16* wb = WT + (size_t)(wave * 16 + l15) * 256 + g * 8;
        f32x4 acc = (f32x4){0.f, 0.f, 0.f, 0.f};
#pragma unroll
        for (int kt = 0; kt < 8; kt++) {
            half8 af = *(const half8*)&sAX[l15][kt * 32 + g * 8];
            half8 bf = *(const half8*)(wb + kt * 32);
            acc = __builtin_amdgcn_mfma_f32_16x16x32_f16(af, bf, acc, 0, 0, 0);
        }
        int o = wave * 16 + l15;
        float scale = gam[o] * rsqrtf(var[o] + 1e-5f);
        float bias = bet[o];
        float mean = mu[o];
        float bb = bl[o];
#pragma unroll
        for (int r = 0; r < 4; r++) {
            float hv = acc[r] + bb;
            hv = (hv - mean) * scale + bias;
            hv = fmaxf(hv, 0.f);
            outp[(size_t)(node0 + g * 4 + r) * NHID + o] = (_Float16)hv;
        }
    }
}

// ---------------- MFMA edge classifier (r14 structure, dst-sorted order) ----------------
// 256 threads (4 waves), 64 CSR-slots/tile, grid-stride, grid=512. Processing in
// dst-sorted CSR order: each tile has ~4 distinct dst nodes (runs of avg deg 16)
// -> hd gathers become L1 broadcasts. s from ssrc (contiguous), e from eperm
// (contiguous), d=dst[e] (L2-resident 3.2MB). out written at original edge id.
__global__ __launch_bounds__(256, 1) void classifier_mfma(
    const _Float16* __restrict__ h2f, const int* __restrict__ ssrc,
    const int* __restrict__ eperm, const int* __restrict__ dst,
    const float* __restrict__ attr, const float* __restrict__ tab,
    const _Float16* __restrict__ W1T, const float* __restrict__ bc1,
    const _Float16* __restrict__ W2T, const float* __restrict__ bc2,
    const _Float16* __restrict__ W3T, const float* __restrict__ bc3,
    float* __restrict__ out, int E, int ntiles) {
    __shared__ _Float16 repr[EPB][RP];    // 37888 B
    __shared__ _Float16 z1s[EPB][Z1P];    // 17408 B
    _Float16* z2f = &repr[0][0];          // [EPB][Z2P] aliases repr

    int tid = threadIdx.x;
    int lane = tid & 63;
    int wave = tid >> 6;
    int l15 = lane & 15;
    int g = lane >> 4;

    // persistent B fragments: 2 ntiles x 9 kt (96 VGPR)
    half8 B1[2][9];
#pragma unroll
    for (int nn = 0; nn < 2; nn++) {
        const _Float16* wb = W1T + (size_t)((2 * wave + nn) * 16 + l15) * 288 + g * 8;
#pragma unroll
        for (int kt = 0; kt < 9; kt++) B1[nn][kt] = *(const half8*)(wb + kt * 32);
    }
    float4 bias1v[2];
#pragma unroll
    for (int nn = 0; nn < 2; nn++)
        bias1v[nn] = *(const float4*)&bc1[(2 * wave + nn) * 16 + g * 4];
    half8 B2[4];
    const _Float16* w2base = W2T + (size_t)(wave * 16 + l15) * 128 + g * 8;
#pragma unroll
    for (int kt = 0; kt < 4; kt++) B2[kt] = *(const half8*)(w2base + kt * 32);
    float4 bias2v = *(const float4*)&bc2[wave * 16 + g * 4];
    half8 B3[2];
#pragma unroll
    for (int kt = 0; kt < 2; kt++)
        B3[kt] = *(const half8*)(W3T + (size_t)l15 * 64 + kt * 32 + g * 8);
    float b3_0 = bc3[0], b3_1 = bc3[1], b3_2 = bc3[2];

    for (int t = blockIdx.x; t < ntiles; t += gridDim.x) {
        int e0 = t * EPB;
        { // ---- stage repr: 4 threads/edge-slot, batched 16B loads
            int el = tid >> 2, p = tid & 3;
            int slot = e0 + el; if (slot >= E) slot = E - 1;
            int s = ssrc[slot];           // contiguous
            int e = eperm[slot];          // contiguous
            int d = dst[e];               // 4B, L2-resident
            const half8* hs = (const half8*)(h2f + (size_t)s * NHID + p * 32);
            const half8* hd = (const half8*)(h2f + (size_t)d * NHID + p * 32);
            half8* r = (half8*)&repr[el][0];
#pragma unroll
            for (int j = 0; j < 4; j++) r[p * 4 + j] = hs[j];
#pragma unroll
            for (int j = 0; j < 4; j++) r[16 + p * 4 + j] = hd[j];
            const float* ssrcp = (p < 2) ? (attr + (size_t)e * 16 + p * 8)
                                         : (tab + (size_t)e * 16 + (p - 2) * 8);
            int doff = (p < 2) ? (32 + p) : (34 + (p - 2));
            float4 a = ((const float4*)ssrcp)[0], b = ((const float4*)ssrcp)[1];
            half8 v;
            v[0] = (_Float16)a.x; v[1] = (_Float16)a.y; v[2] = (_Float16)a.z; v[3] = (_Float16)a.w;
            v[4] = (_Float16)b.x; v[5] = (_Float16)b.y; v[6] = (_Float16)b.z; v[7] = (_Float16)b.w;
            r[doff] = v;
        }
        __syncthreads();

        // ---- GEMM1 (swapped): D[row=out][col=edge]; 4 atiles x 2 ntiles
#pragma unroll
        for (int at = 0; at < 4; at++) {
            const _Float16* ab = &repr[at * 16 + l15][g * 8];
            f32x4 acc0 = (f32x4){bias1v[0].x, bias1v[0].y, bias1v[0].z, bias1v[0].w};
            f32x4 acc1 = (f32x4){bias1v[1].x, bias1v[1].y, bias1v[1].z, bias1v[1].w};
#pragma unroll
            for (int kt = 0; kt < 9; kt++) {
                half8 af = *(const half8*)(ab + kt * 32);
                acc0 = __builtin_amdgcn_mfma_f32_16x16x32_f16(B1[0][kt], af, acc0, 0, 0, 0);
                acc1 = __builtin_amdgcn_mfma_f32_16x16x32_f16(B1[1][kt], af, acc1, 0, 0, 0);
            }
            half4v p0, p1;
#pragma unroll
            for (int r = 0; r < 4; r++) {
                p0[r] = (_Float16)fmaxf(acc0[r], 0.f);
                p1[r] = (_Float16)fmaxf(acc1[r], 0.f);
            }
            *(half4v*)&z1s[at * 16 + l15][(2 * wave + 0) * 16 + g * 4] = p0;
            *(half4v*)&z1s[at * 16 + l15][(2 * wave + 1) * 16 + g * 4] = p1;
        }
        __syncthreads();

        // ---- GEMM2 (swapped): 4 atiles x 1 ntile -> z2f (aliases repr)
#pragma unroll
        for (int a = 0; a < 4; a++) {
            const _Float16* ab = &z1s[a * 16 + l15][g * 8];
            f32x4 acc2 = (f32x4){bias2v.x, bias2v.y, bias2v.z, bias2v.w};
#pragma unroll
            for (int kt = 0; kt < 4; kt++)
                acc2 = __builtin_amdgcn_mfma_f32_16x16x32_f16(B2[kt], *(const half8*)(ab + kt * 32),
                                                              acc2, 0, 0, 0);
            half4v p;
#pragma unroll
            for (int r = 0; r < 4; r++) p[r] = (_Float16)fmaxf(acc2[r], 0.f);
            *(half4v*)&z2f[(size_t)(a * 16 + l15) * Z2P + wave * 16 + g * 4] = p;
        }
        __syncthreads();

        // ---- GEMM3 (swapped): wave handles atile=wave; g=0 lanes hold c=0..2
        {
            const _Float16* ab = z2f + (size_t)(wave * 16 + l15) * Z2P + g * 8;
            f32x4 acc3 = (f32x4){0.f, 0.f, 0.f, 0.f};
#pragma unroll
            for (int kt = 0; kt < 2; kt++)
                acc3 = __builtin_amdgcn_mfma_f32_16x16x32_f16(B3[kt], *(const half8*)(ab + kt * 32),
                                                              acc3, 0, 0, 0);
            if (g == 0) {
                int slot = e0 + wave * 16 + l15;
                if (slot < E) {
                    int e = eperm[slot];
                    out[(size_t)e * 3 + 0] = acc3[0] + b3_0;
                    out[(size_t)e * 3 + 1] = acc3[1] + b3_1;
                    out[(size_t)e * 3 + 2] = acc3[2] + b3_2;
                }
            }
        }
        __syncthreads();   // protect repr/z2f before next tile's staging
    }
}

extern "C" void kernel_launch(void* const* d_in, const int* in_sizes, int n_in,
                              void* d_out, int out_size, void* d_ws, size_t ws_size,
                              hipStream_t stream) {
    const float* x    = (const float*)d_in[0];
    const int*   ei   = (const int*)d_in[1];
    const float* attr = (const float*)d_in[2];
    const float* tab  = (const float*)d_in[3];
    const float* W1l  = (const float*)d_in[4];
    const float* b1l  = (const float*)d_in[5];
    const float* W1r  = (const float*)d_in[6];
    const float* W2l  = (const float*)d_in[7];
    const float* b2l  = (const float*)d_in[8];
    const float* W2r  = (const float*)d_in[9];
    const float* g1   = (const float*)d_in[10];
    const float* be1  = (const float*)d_in[11];
    const float* m1   = (const float*)d_in[12];
    const float* v1   = (const float*)d_in[13];
    const float* g2   = (const float*)d_in[14];
    const float* be2  = (const float*)d_in[15];
    const float* m2   = (const float*)d_in[16];
    const float* v2   = (const float*)d_in[17];
    const float* Wc1  = (const float*)d_in[18];
    const float* bc1  = (const float*)d_in[19];
    const float* Wc2  = (const float*)d_in[20];
    const float* bc2  = (const float*)d_in[21];
    const float* Wc3  = (const float*)d_in[22];
    const float* bc3  = (const float*)d_in[23];
    float* out = (float*)d_out;

    const int N = in_sizes[0] / NHID;     // 50000
    const int E = in_sizes[1] / 2;        // 800000

    // workspace layout (bytes)
    char* ws = (char*)d_ws;
    int*       rowptr = (int*)(ws + 0);                 // N+1 ints
    int*       cursor = (int*)(ws + 204800);            // N ints
    int*       deg    = (int*)(ws + 409600);            // N ints
    int*       ssrc   = (int*)(ws + 614400);            // E ints
    int*       bsum   = (int*)(ws + 3814400);
    int*       bpre   = (int*)(ws + 3815424);
    _Float16*  W1T    = (_Float16*)(ws + 3816448);      // 128x288
    _Float16*  W2T    = (_Float16*)(ws + 3890176);      // 64x128
    _Float16*  W3T    = (_Float16*)(ws + 3906560);      // 16x64
    _Float16*  WT1    = (_Float16*)(ws + 3908608);      // 128x256
    _Float16*  WT2    = (_Float16*)(ws + 3974144);      // 128x256
    _Float16*  xf     = (_Float16*)(ws + 4039680);      // N*128 f16
    _Float16*  h1f    = (_Float16*)(ws + 4039680 + (size_t)N * NHID * 2);
    _Float16*  h2f    = (_Float16*)(ws + 4039680 + 2 * (size_t)N * NHID * 2);
    int*       eperm  = (int*)(ws + 4039680 + 3 * (size_t)N * NHID * 2);  // E ints

    const int* src = ei;
    const int* dst = ei + E;

    int eblocks = (E + 255) / 256;
    int cblocks = (N + 255) / 256;        // 196
    int nblocks16 = (N + 15) / 16;        // 3125
    int ntiles  = (E + EPB - 1) / EPB;    // 12500
    int cgrid   = 512;                    // exactly 2 blocks/CU resident
    if (cgrid > ntiles) cgrid = ntiles;
    int n8      = N * NHID / 8;           // 800000

    // 0) prep weights (f16, transposed) + f16 cast of x
    prep_weights<<<144, 256, 0, stream>>>(Wc1, Wc2, Wc3, W1l, W1r, W2l, W2r,
                                          W1T, W2T, W3T, WT1, WT2);
    cast_f32_f16<<<1024, 256, 0, stream>>>(x, xf, n8);
    // 1) CSR build (ssrc + eperm)
    zero_kernel<<<16, 256, 0, stream>>>((float*)deg, 204800 / 16);
    count_kernel<<<eblocks, 256, 0, stream>>>(dst, deg, E);
    csr_reduce<<<cblocks, 256, 0, stream>>>(deg, bsum, N);
    csr_scan_partials<<<1, 256, 0, stream>>>(bsum, bpre, rowptr, cblocks, N);
    csr_emit<<<cblocks, 256, 0, stream>>>(deg, bpre, rowptr, cursor, N);
    fill_kernel<<<eblocks, 256, 0, stream>>>(src, dst, cursor, ssrc, eperm, E);
    // 2) layer 1 -> h1f (f16)
    sage_layer<<<nblocks16, 512, 0, stream>>>(xf, rowptr, ssrc, WT1, b1l,
                                              g1, be1, m1, v1, h1f, N);
    // 3) layer 2 -> h2f (f16)
    sage_layer<<<nblocks16, 512, 0, stream>>>(h1f, rowptr, ssrc, WT2, b2l,
                                              g2, be2, m2, v2, h2f, N);
    // 4) MFMA edge classifier (dst-sorted order: hd gathers L1-broadcast)
    classifier_mfma<<<cgrid, 256, 0, stream>>>(h2f, ssrc, eperm, dst, attr, tab,
                                               W1T, bc1, W2T, bc2, W3T, bc3,
                                               out, E, ntiles);
}

// Round 18
// 310.523 us; speedup vs baseline: 1.0007x; 1.0007x over previous
//
#include <hip/hip_runtime.h>
#include <stdint.h>

#define NHID 128
#define EPB 64          // edges per classifier tile
#define RP  296         // padded repr row (f16): 592B stride, 16B-aligned
#define Z1P 136         // padded z1 row (f16): 272B stride, 16B-aligned
#define Z2P 72          // padded z2 row (f16): 144B stride, 16B-aligned

typedef _Float16 half8 __attribute__((ext_vector_type(8)));
typedef _Float16 half4v __attribute__((ext_vector_type(4)));
typedef float f32x4 __attribute__((ext_vector_type(4)));

// ---------------- zero (16B granularity) ----------------
__global__ void zero_kernel(float* __restrict__ p, size_t n4) {
    size_t i = (size_t)blockIdx.x * blockDim.x + threadIdx.x;
    size_t stride = (size_t)gridDim.x * blockDim.x;
    float4* p4 = (float4*)p;
    float4 z = make_float4(0.f, 0.f, 0.f, 0.f);
    for (size_t j = i; j < n4; j += stride) p4[j] = z;
}

// ---------------- fp32 -> f16 cast (8 elems/thread) ----------------
__global__ void cast_f32_f16(const float* __restrict__ in, _Float16* __restrict__ outp,
                             int n8) {
    int i = blockIdx.x * 256 + threadIdx.x;
    int stride = gridDim.x * 256;
    for (int j = i; j < n8; j += stride) {
        float4 a = ((const float4*)in)[2 * j];
        float4 b = ((const float4*)in)[2 * j + 1];
        half8 v;
        v[0] = (_Float16)a.x; v[1] = (_Float16)a.y; v[2] = (_Float16)a.z; v[3] = (_Float16)a.w;
        v[4] = (_Float16)b.x; v[5] = (_Float16)b.y; v[6] = (_Float16)b.z; v[7] = (_Float16)b.w;
        ((half8*)outp)[j] = v;
    }
}

// ---------------- weight prep: fp32 -> f16, transposed ----------------
__global__ void prep_weights(const float* __restrict__ Wc1, const float* __restrict__ Wc2,
                             const float* __restrict__ Wc3,
                             const float* __restrict__ W1l, const float* __restrict__ W1r,
                             const float* __restrict__ W2l, const float* __restrict__ W2r,
                             _Float16* __restrict__ W1T, _Float16* __restrict__ W2T,
                             _Float16* __restrict__ W3T,
                             _Float16* __restrict__ WT1, _Float16* __restrict__ WT2) {
    int tid = blockIdx.x * 256 + threadIdx.x;
    if (tid < 288 * 128) {
        int n = tid / 288, k = tid % 288;
        W1T[tid] = (_Float16)Wc1[(size_t)k * 128 + n];
    }
    if (tid < 64 * 128) {
        int n = tid / 128, k = tid % 128;
        W2T[tid] = (_Float16)Wc2[(size_t)k * 64 + n];
    }
    if (tid < 16 * 64) {
        int n = tid / 64, k = tid % 64;
        W3T[tid] = (n < 3) ? (_Float16)Wc3[(size_t)k * 3 + n] : (_Float16)0.f;
    }
    if (tid < 128 * 256) {
        int n = tid / 256, k = tid % 256;
        WT1[tid] = (k < 128) ? (_Float16)W1l[(size_t)k * 128 + n]
                             : (_Float16)W1r[(size_t)(k - 128) * 128 + n];
        WT2[tid] = (k < 128) ? (_Float16)W2l[(size_t)k * 128 + n]
                             : (_Float16)W2r[(size_t)(k - 128) * 128 + n];
    }
}

// ---------------- CSR build ----------------
__global__ void count_kernel(const int* __restrict__ dst, int* __restrict__ deg, int E) {
    int e = blockIdx.x * 256 + threadIdx.x;
    if (e < E) atomicAdd(&deg[dst[e]], 1);
}

__global__ __launch_bounds__(256) void csr_reduce(const int* __restrict__ deg,
                                                  int* __restrict__ bsum, int N) {
    __shared__ int b[256];
    int t = threadIdx.x;
    int i = blockIdx.x * 256 + t;
    int v = (i < N) ? deg[i] : 0;
    b[t] = v;
    __syncthreads();
#pragma unroll
    for (int off = 128; off > 0; off >>= 1) {
        if (t < off) b[t] += b[t + off];
        __syncthreads();
    }
    if (t == 0) bsum[blockIdx.x] = b[0];
}

__global__ __launch_bounds__(256) void csr_scan_partials(const int* __restrict__ bsum,
                                                         int* __restrict__ bpre,
                                                         int* __restrict__ rowptr,
                                                         int nb, int N) {
    __shared__ int b[256];
    int t = threadIdx.x;
    int v = (t < nb) ? bsum[t] : 0;
    b[t] = v;
    __syncthreads();
    int x = v;
#pragma unroll
    for (int off = 1; off < 256; off <<= 1) {
        int y = (t >= off) ? b[t - off] : 0;
        __syncthreads();
        x += y;
        b[t] = x;
        __syncthreads();
    }
    if (t < nb) bpre[t] = x - v;           // exclusive
    if (t == nb - 1) rowptr[N] = x;        // total
}

__global__ __launch_bounds__(256) void csr_emit(const int* __restrict__ deg,
                                                const int* __restrict__ bpre,
                                                int* __restrict__ rowptr,
                                                int* __restrict__ cursor, int N) {
    __shared__ int b[256];
    int t = threadIdx.x;
    int i = blockIdx.x * 256 + t;
    int v = (i < N) ? deg[i] : 0;
    b[t] = v;
    __syncthreads();
    int x = v;
#pragma unroll
    for (int off = 1; off < 256; off <<= 1) {
        int y = (t >= off) ? b[t - off] : 0;
        __syncthreads();
        x += y;
        b[t] = x;
        __syncthreads();
    }
    if (i < N) {
        int excl = bpre[blockIdx.x] + x - v;
        rowptr[i] = excl;
        cursor[i] = excl;
    }
}

__global__ void fill_kernel(const int* __restrict__ src, const int* __restrict__ dst,
                            int* __restrict__ cursor, int* __restrict__ ssrc, int E) {
    int e = blockIdx.x * 256 + threadIdx.x;
    if (e < E) {
        int p = atomicAdd(&cursor[dst[e]], 1);
        ssrc[p] = src[e];
    }
}

// ---------------- fused pull-aggregate + SAGE (MFMA) + BN + ReLU ----------------
// r15 proven body: 512 threads, 16 nodes/block; 2 teams x 16 lanes per node,
// half8 (16B) loads, team walks every-2nd edge, __shfl_xor(.,16) combine.
__global__ __launch_bounds__(512) void sage_layer(
    const _Float16* __restrict__ xin, const int* __restrict__ rowptr,
    const int* __restrict__ ssrc,
    const _Float16* __restrict__ WT, const float* __restrict__ bl,
    const float* __restrict__ gam, const float* __restrict__ bet,
    const float* __restrict__ mu, const float* __restrict__ var,
    _Float16* __restrict__ outp, int N) {
    __shared__ _Float16 sAX[16][264];   // [0:128)=agg, [128:256)=x
    int tid = threadIdx.x;
    int node0 = blockIdx.x * 16;

    { // ---- gather phase
        int i = tid >> 5;              // node slot 0..15
        int lsub = tid & 31;
        int q16 = lsub & 15;           // feature octet (8 halfs = 16B)
        int team = lsub >> 4;          // 0 or 1
        int node = node0 + i;
        int rs = rowptr[node], re = rowptr[node + 1];
        float acc[8];
#pragma unroll
        for (int c = 0; c < 8; c++) acc[c] = 0.f;
        int e = rs + team;
        for (; e + 6 < re; e += 8) {   // edges e, e+2, e+4, e+6 (this team)
            int s0 = ssrc[e], s1 = ssrc[e + 2], s2 = ssrc[e + 4], s3 = ssrc[e + 6];
            half8 v0 = *(const half8*)&xin[(size_t)s0 * NHID + q16 * 8];
            half8 v1 = *(const half8*)&xin[(size_t)s1 * NHID + q16 * 8];
            half8 v2 = *(const half8*)&xin[(size_t)s2 * NHID + q16 * 8];
            half8 v3 = *(const half8*)&xin[(size_t)s3 * NHID + q16 * 8];
#pragma unroll
            for (int c = 0; c < 8; c++)
                acc[c] += ((float)v0[c] + (float)v1[c]) + ((float)v2[c] + (float)v3[c]);
        }
        for (; e < re; e += 2) {
            half8 v = *(const half8*)&xin[(size_t)ssrc[e] * NHID + q16 * 8];
#pragma unroll
            for (int c = 0; c < 8; c++) acc[c] += (float)v[c];
        }
        // combine team partials (lane ^ 16 = other team, same node/q16)
#pragma unroll
        for (int c = 0; c < 8; c++) acc[c] += __shfl_xor(acc[c], 16);
        int deg = re - rs;
        float inv = (deg > 0) ? (1.0f / (float)deg) : 0.f;
        if (team == 0) {
            half8 av;
#pragma unroll
            for (int c = 0; c < 8; c++) av[c] = (_Float16)(acc[c] * inv);
            *(half8*)&sAX[i][q16 * 8] = av;
            *(half8*)&sAX[i][128 + q16 * 8] =
                *(const half8*)&xin[(size_t)node * NHID + q16 * 8];
        }
    }
    __syncthreads();

    // ---- MFMA GEMM: wave = ntile
    {
        int lane = tid & 63;
        int wave = tid >> 6;          // 0..7
        int l15 = lane & 15;
        int g = lane >> 4;
        const _Float16* wb = WT + (size_t)(wave * 16 + l15) * 256 + g * 8;
        f32x4 acc = (f32x4){0.f, 0.f, 0.f, 0.f};
#pragma unroll
        for (int kt = 0; kt < 8; kt++) {
            half8 af = *(const half8*)&sAX[l15][kt * 32 + g * 8];
            half8 bf = *(const half8*)(wb + kt * 32);
            acc = __builtin_amdgcn_mfma_f32_16x16x32_f16(af, bf, acc, 0, 0, 0);
        }
        int o = wave * 16 + l15;
        float scale = gam[o] * rsqrtf(var[o] + 1e-5f);
        float bias = bet[o];
        float mean = mu[o];
        float bb = bl[o];
#pragma unroll
        for (int r = 0; r < 4; r++) {
            float hv = acc[r] + bb;
            hv = (hv - mean) * scale + bias;
            hv = fmaxf(hv, 0.f);
            outp[(size_t)(node0 + g * 4 + r) * NHID + o] = (_Float16)hv;
        }
    }
}

// ---------------- MFMA edge classifier (exact r14 proven: 113.5 us) ----------------
// 256 threads (4 waves), 64 edges/tile, grid-stride, grid=512, aliased z2f,
// 4 barriers/tile. Swapped-operand MFMA -> vectorized epilogues. VGPR 96.
__global__ __launch_bounds__(256, 1) void classifier_mfma(
    const _Float16* __restrict__ h2f, const int* __restrict__ src,
    const int* __restrict__ dst,
    const float* __restrict__ attr, const float* __restrict__ tab,
    const _Float16* __restrict__ W1T, const float* __restrict__ bc1,
    const _Float16* __restrict__ W2T, const float* __restrict__ bc2,
    const _Float16* __restrict__ W3T, const float* __restrict__ bc3,
    float* __restrict__ out, int E, int ntiles) {
    __shared__ _Float16 repr[EPB][RP];    // 37888 B
    __shared__ _Float16 z1s[EPB][Z1P];    // 17408 B
    _Float16* z2f = &repr[0][0];          // [EPB][Z2P] aliases repr

    int tid = threadIdx.x;
    int lane = tid & 63;
    int wave = tid >> 6;
    int l15 = lane & 15;
    int g = lane >> 4;

    // persistent B fragments: 2 ntiles x 9 kt
    half8 B1[2][9];
#pragma unroll
    for (int nn = 0; nn < 2; nn++) {
        const _Float16* wb = W1T + (size_t)((2 * wave + nn) * 16 + l15) * 288 + g * 8;
#pragma unroll
        for (int kt = 0; kt < 9; kt++) B1[nn][kt] = *(const half8*)(wb + kt * 32);
    }
    // row-indexed biases (out-channel = g*4+r)
    float4 bias1v[2];
#pragma unroll
    for (int nn = 0; nn < 2; nn++)
        bias1v[nn] = *(const float4*)&bc1[(2 * wave + nn) * 16 + g * 4];
    half8 B2[4];
    const _Float16* w2base = W2T + (size_t)(wave * 16 + l15) * 128 + g * 8;
#pragma unroll
    for (int kt = 0; kt < 4; kt++) B2[kt] = *(const half8*)(w2base + kt * 32);
    float4 bias2v = *(const float4*)&bc2[wave * 16 + g * 4];
    half8 B3[2];
#pragma unroll
    for (int kt = 0; kt < 2; kt++)
        B3[kt] = *(const half8*)(W3T + (size_t)l15 * 64 + kt * 32 + g * 8);
    float b3_0 = bc3[0], b3_1 = bc3[1], b3_2 = bc3[2];

    for (int t = blockIdx.x; t < ntiles; t += gridDim.x) {
        int e0 = t * EPB;
        { // ---- stage repr: 4 threads/edge, batched 16B loads
            int el = tid >> 2, p = tid & 3;
            int e = e0 + el; if (e >= E) e = E - 1;
            int s = src[e], d = dst[e];
            const half8* hs = (const half8*)(h2f + (size_t)s * NHID + p * 32);
            const half8* hd = (const half8*)(h2f + (size_t)d * NHID + p * 32);
            half8* r = (half8*)&repr[el][0];
#pragma unroll
            for (int j = 0; j < 4; j++) r[p * 4 + j] = hs[j];
#pragma unroll
            for (int j = 0; j < 4; j++) r[16 + p * 4 + j] = hd[j];
            const float* ssrcp = (p < 2) ? (attr + (size_t)e * 16 + p * 8)
                                         : (tab + (size_t)e * 16 + (p - 2) * 8);
            int doff = (p < 2) ? (32 + p) : (34 + (p - 2));
            float4 a = ((const float4*)ssrcp)[0], b = ((const float4*)ssrcp)[1];
            half8 v;
            v[0] = (_Float16)a.x; v[1] = (_Float16)a.y; v[2] = (_Float16)a.z; v[3] = (_Float16)a.w;
            v[4] = (_Float16)b.x; v[5] = (_Float16)b.y; v[6] = (_Float16)b.z; v[7] = (_Float16)b.w;
            r[doff] = v;
        }
        __syncthreads();

        // ---- GEMM1 (swapped): D[row=out][col=edge]; 4 atiles x 2 ntiles
#pragma unroll
        for (int at = 0; at < 4; at++) {
            const _Float16* ab = &repr[at * 16 + l15][g * 8];
            f32x4 acc0 = (f32x4){bias1v[0].x, bias1v[0].y, bias1v[0].z, bias1v[0].w};
            f32x4 acc1 = (f32x4){bias1v[1].x, bias1v[1].y, bias1v[1].z, bias1v[1].w};
#pragma unroll
            for (int kt = 0; kt < 9; kt++) {
                half8 af = *(const half8*)(ab + kt * 32);
                acc0 = __builtin_amdgcn_mfma_f32_16x16x32_f16(B1[0][kt], af, acc0, 0, 0, 0);
                acc1 = __builtin_amdgcn_mfma_f32_16x16x32_f16(B1[1][kt], af, acc1, 0, 0, 0);
            }
            half4v p0, p1;
#pragma unroll
            for (int r = 0; r < 4; r++) {
                p0[r] = (_Float16)fmaxf(acc0[r], 0.f);
                p1[r] = (_Float16)fmaxf(acc1[r], 0.f);
            }
            *(half4v*)&z1s[at * 16 + l15][(2 * wave + 0) * 16 + g * 4] = p0;
            *(half4v*)&z1s[at * 16 + l15][(2 * wave + 1) * 16 + g * 4] = p1;
        }
        __syncthreads();

        // ---- GEMM2 (swapped): 4 atiles x 1 ntile -> z2f (aliases repr)
#pragma unroll
        for (int a = 0; a < 4; a++) {
            const _Float16* ab = &z1s[a * 16 + l15][g * 8];
            f32x4 acc2 = (f32x4){bias2v.x, bias2v.y, bias2v.z, bias2v.w};
#pragma unroll
            for (int kt = 0; kt < 4; kt++)
                acc2 = __builtin_amdgcn_mfma_f32_16x16x32_f16(B2[kt], *(const half8*)(ab + kt * 32),
                                                              acc2, 0, 0, 0);
            half4v p;
#pragma unroll
            for (int r = 0; r < 4; r++) p[r] = (_Float16)fmaxf(acc2[r], 0.f);
            *(half4v*)&z2f[(size_t)(a * 16 + l15) * Z2P + wave * 16 + g * 4] = p;
        }
        __syncthreads();

        // ---- GEMM3 (swapped): wave handles atile=wave; g=0 lanes hold c=0..2
        {
            const _Float16* ab = z2f + (size_t)(wave * 16 + l15) * Z2P + g * 8;
            f32x4 acc3 = (f32x4){0.f, 0.f, 0.f, 0.f};
#pragma unroll
            for (int kt = 0; kt < 2; kt++)
                acc3 = __builtin_amdgcn_mfma_f32_16x16x32_f16(B3[kt], *(const half8*)(ab + kt * 32),
                                                              acc3, 0, 0, 0);
            if (g == 0) {
                int e = e0 + wave * 16 + l15;
                if (e < E) {
                    out[(size_t)e * 3 + 0] = acc3[0] + b3_0;
                    out[(size_t)e * 3 + 1] = acc3[1] + b3_1;
                    out[(size_t)e * 3 + 2] = acc3[2] + b3_2;
                }
            }
        }
        __syncthreads();   // protect repr/z2f before next tile's staging
    }
}

extern "C" void kernel_launch(void* const* d_in, const int* in_sizes, int n_in,
                              void* d_out, int out_size, void* d_ws, size_t ws_size,
                              hipStream_t stream) {
    const float* x    = (const float*)d_in[0];
    const int*   ei   = (const int*)d_in[1];
    const float* attr = (const float*)d_in[2];
    const float* tab  = (const float*)d_in[3];
    const float* W1l  = (const float*)d_in[4];
    const float* b1l  = (const float*)d_in[5];
    const float* W1r  = (const float*)d_in[6];
    const float* W2l  = (const float*)d_in[7];
    const float* b2l  = (const float*)d_in[8];
    const float* W2r  = (const float*)d_in[9];
    const float* g1   = (const float*)d_in[10];
    const float* be1  = (const float*)d_in[11];
    const float* m1   = (const float*)d_in[12];
    const float* v1   = (const float*)d_in[13];
    const float* g2   = (const float*)d_in[14];
    const float* be2  = (const float*)d_in[15];
    const float* m2   = (const float*)d_in[16];
    const float* v2   = (const float*)d_in[17];
    const float* Wc1  = (const float*)d_in[18];
    const float* bc1  = (const float*)d_in[19];
    const float* Wc2  = (const float*)d_in[20];
    const float* bc2  = (const float*)d_in[21];
    const float* Wc3  = (const float*)d_in[22];
    const float* bc3  = (const float*)d_in[23];
    float* out = (float*)d_out;

    const int N = in_sizes[0] / NHID;     // 50000
    const int E = in_sizes[1] / 2;        // 800000

    // workspace layout (bytes)
    char* ws = (char*)d_ws;
    int*       rowptr = (int*)(ws + 0);                 // N+1 ints
    int*       cursor = (int*)(ws + 204800);            // N ints
    int*       deg    = (int*)(ws + 409600);            // N ints
    int*       ssrc   = (int*)(ws + 614400);            // E ints
    int*       bsum   = (int*)(ws + 3814400);
    int*       bpre   = (int*)(ws + 3815424);
    _Float16*  W1T    = (_Float16*)(ws + 3816448);      // 128x288
    _Float16*  W2T    = (_Float16*)(ws + 3890176);      // 64x128
    _Float16*  W3T    = (_Float16*)(ws + 3906560);      // 16x64
    _Float16*  WT1    = (_Float16*)(ws + 3908608);      // 128x256
    _Float16*  WT2    = (_Float16*)(ws + 3974144);      // 128x256
    _Float16*  xf     = (_Float16*)(ws + 4039680);      // N*128 f16
    _Float16*  h1f    = (_Float16*)(ws + 4039680 + (size_t)N * NHID * 2);
    _Float16*  h2f    = (_Float16*)(ws + 4039680 + 2 * (size_t)N * NHID * 2);

    const int* src = ei;
    const int* dst = ei + E;

    int eblocks = (E + 255) / 256;
    int cblocks = (N + 255) / 256;        // 196
    int nblocks16 = (N + 15) / 16;        // 3125
    int ntiles  = (E + EPB - 1) / EPB;    // 12500
    int cgrid   = 512;                    // exactly 2 blocks/CU resident
    if (cgrid > ntiles) cgrid = ntiles;
    int n8      = N * NHID / 8;           // 800000

    // 0) prep weights (f16, transposed) + f16 cast of x
    prep_weights<<<144, 256, 0, stream>>>(Wc1, Wc2, Wc3, W1l, W1r, W2l, W2r,
                                          W1T, W2T, W3T, WT1, WT2);
    cast_f32_f16<<<1024, 256, 0, stream>>>(x, xf, n8);
    // 1) CSR build
    zero_kernel<<<16, 256, 0, stream>>>((float*)deg, 204800 / 16);
    count_kernel<<<eblocks, 256, 0, stream>>>(dst, deg, E);
    csr_reduce<<<cblocks, 256, 0, stream>>>(deg, bsum, N);
    csr_scan_partials<<<1, 256, 0, stream>>>(bsum, bpre, rowptr, cblocks, N);
    csr_emit<<<cblocks, 256, 0, stream>>>(deg, bpre, rowptr, cursor, N);
    fill_kernel<<<eblocks, 256, 0, stream>>>(src, dst, cursor, ssrc, E);
    // 2) layer 1 -> h1f (f16)
    sage_layer<<<nblocks16, 512, 0, stream>>>(xf, rowptr, ssrc, WT1, b1l,
                                              g1, be1, m1, v1, h1f, N);
    // 3) layer 2 -> h2f (f16)
    sage_layer<<<nblocks16, 512, 0, stream>>>(h1f, rowptr, ssrc, WT2, b2l,
                                              g2, be2, m2, v2, h2f, N);
    // 4) MFMA edge classifier (r14 exact: 4-barrier, aliased z2f)
    classifier_mfma<<<cgrid, 256, 0, stream>>>(h2f, src, dst, attr, tab,
                                               W1T, bc1, W2T, bc2, W3T, bc3,
                                               out, E, ntiles);
}

// Round 19
// 298.131 us; speedup vs baseline: 1.0423x; 1.0416x over previous
//
#include <hip/hip_runtime.h>
#include <stdint.h>

#define NHID 128
#define EPB 64          // edges per classifier tile
#define RP  296         // padded repr row (f16): 592B stride, 16B-aligned
#define Z1P 136         // padded z1 row (f16): 272B stride, 16B-aligned
#define Z2P 72          // padded z2 row (f16): 144B stride, 16B-aligned

typedef _Float16 half8 __attribute__((ext_vector_type(8)));
typedef _Float16 half4v __attribute__((ext_vector_type(4)));
typedef float f32x4 __attribute__((ext_vector_type(4)));

// ---------------- zero (16B granularity) ----------------
__global__ void zero_kernel(float* __restrict__ p, size_t n4) {
    size_t i = (size_t)blockIdx.x * blockDim.x + threadIdx.x;
    size_t stride = (size_t)gridDim.x * blockDim.x;
    float4* p4 = (float4*)p;
    float4 z = make_float4(0.f, 0.f, 0.f, 0.f);
    for (size_t j = i; j < n4; j += stride) p4[j] = z;
}

// ---------------- fp32 -> f16 cast (8 elems/thread) ----------------
__global__ void cast_f32_f16(const float* __restrict__ in, _Float16* __restrict__ outp,
                             int n8) {
    int i = blockIdx.x * 256 + threadIdx.x;
    int stride = gridDim.x * 256;
    for (int j = i; j < n8; j += stride) {
        float4 a = ((const float4*)in)[2 * j];
        float4 b = ((const float4*)in)[2 * j + 1];
        half8 v;
        v[0] = (_Float16)a.x; v[1] = (_Float16)a.y; v[2] = (_Float16)a.z; v[3] = (_Float16)a.w;
        v[4] = (_Float16)b.x; v[5] = (_Float16)b.y; v[6] = (_Float16)b.z; v[7] = (_Float16)b.w;
        ((half8*)outp)[j] = v;
    }
}

// ---------------- weight prep: fp32 -> f16, transposed ----------------
__global__ void prep_weights(const float* __restrict__ Wc1, const float* __restrict__ Wc2,
                             const float* __restrict__ Wc3,
                             const float* __restrict__ W1l, const float* __restrict__ W1r,
                             const float* __restrict__ W2l, const float* __restrict__ W2r,
                             _Float16* __restrict__ W1T, _Float16* __restrict__ W2T,
                             _Float16* __restrict__ W3T,
                             _Float16* __restrict__ WT1, _Float16* __restrict__ WT2) {
    int tid = blockIdx.x * 256 + threadIdx.x;
    if (tid < 288 * 128) {
        int n = tid / 288, k = tid % 288;
        W1T[tid] = (_Float16)Wc1[(size_t)k * 128 + n];
    }
    if (tid < 64 * 128) {
        int n = tid / 128, k = tid % 128;
        W2T[tid] = (_Float16)Wc2[(size_t)k * 64 + n];
    }
    if (tid < 16 * 64) {
        int n = tid / 64, k = tid % 64;
        W3T[tid] = (n < 3) ? (_Float16)Wc3[(size_t)k * 3 + n] : (_Float16)0.f;
    }
    if (tid < 128 * 256) {
        int n = tid / 256, k = tid % 256;
        WT1[tid] = (k < 128) ? (_Float16)W1l[(size_t)k * 128 + n]
                             : (_Float16)W1r[(size_t)(k - 128) * 128 + n];
        WT2[tid] = (k < 128) ? (_Float16)W2l[(size_t)k * 128 + n]
                             : (_Float16)W2r[(size_t)(k - 128) * 128 + n];
    }
}

// ---------------- CSR build ----------------
__global__ void count_kernel(const int* __restrict__ dst, int* __restrict__ deg, int E) {
    int e = blockIdx.x * 256 + threadIdx.x;
    if (e < E) atomicAdd(&deg[dst[e]], 1);
}

__global__ __launch_bounds__(256) void csr_reduce(const int* __restrict__ deg,
                                                  int* __restrict__ bsum, int N) {
    __shared__ int b[256];
    int t = threadIdx.x;
    int i = blockIdx.x * 256 + t;
    int v = (i < N) ? deg[i] : 0;
    b[t] = v;
    __syncthreads();
#pragma unroll
    for (int off = 128; off > 0; off >>= 1) {
        if (t < off) b[t] += b[t + off];
        __syncthreads();
    }
    if (t == 0) bsum[blockIdx.x] = b[0];
}

__global__ __launch_bounds__(256) void csr_scan_partials(const int* __restrict__ bsum,
                                                         int* __restrict__ bpre,
                                                         int* __restrict__ rowptr,
                                                         int nb, int N) {
    __shared__ int b[256];
    int t = threadIdx.x;
    int v = (t < nb) ? bsum[t] : 0;
    b[t] = v;
    __syncthreads();
    int x = v;
#pragma unroll
    for (int off = 1; off < 256; off <<= 1) {
        int y = (t >= off) ? b[t - off] : 0;
        __syncthreads();
        x += y;
        b[t] = x;
        __syncthreads();
    }
    if (t < nb) bpre[t] = x - v;           // exclusive
    if (t == nb - 1) rowptr[N] = x;        // total
}

__global__ __launch_bounds__(256) void csr_emit(const int* __restrict__ deg,
                                                const int* __restrict__ bpre,
                                                int* __restrict__ rowptr,
                                                int* __restrict__ cursor, int N) {
    __shared__ int b[256];
    int t = threadIdx.x;
    int i = blockIdx.x * 256 + t;
    int v = (i < N) ? deg[i] : 0;
    b[t] = v;
    __syncthreads();
    int x = v;
#pragma unroll
    for (int off = 1; off < 256; off <<= 1) {
        int y = (t >= off) ? b[t - off] : 0;
        __syncthreads();
        x += y;
        b[t] = x;
        __syncthreads();
    }
    if (i < N) {
        int excl = bpre[blockIdx.x] + x - v;
        rowptr[i] = excl;
        cursor[i] = excl;
    }
}

__global__ void fill_kernel(const int* __restrict__ src, const int* __restrict__ dst,
                            int* __restrict__ cursor, int* __restrict__ ssrc, int E) {
    int e = blockIdx.x * 256 + threadIdx.x;
    if (e < E) {
        int p = atomicAdd(&cursor[dst[e]], 1);
        ssrc[p] = src[e];
    }
}

// ---------------- fused pull-aggregate + SAGE (MFMA) + BN + ReLU ----------------
// r15 proven body: 512 threads, 16 nodes/block; 2 teams x 16 lanes per node.
__global__ __launch_bounds__(512) void sage_layer(
    const _Float16* __restrict__ xin, const int* __restrict__ rowptr,
    const int* __restrict__ ssrc,
    const _Float16* __restrict__ WT, const float* __restrict__ bl,
    const float* __restrict__ gam, const float* __restrict__ bet,
    const float* __restrict__ mu, const float* __restrict__ var,
    _Float16* __restrict__ outp, int N) {
    __shared__ _Float16 sAX[16][264];   // [0:128)=agg, [128:256)=x
    int tid = threadIdx.x;
    int node0 = blockIdx.x * 16;

    { // ---- gather phase
        int i = tid >> 5;              // node slot 0..15
        int lsub = tid & 31;
        int q16 = lsub & 15;           // feature octet (8 halfs = 16B)
        int team = lsub >> 4;          // 0 or 1
        int node = node0 + i;
        int rs = rowptr[node], re = rowptr[node + 1];
        float acc[8];
#pragma unroll
        for (int c = 0; c < 8; c++) acc[c] = 0.f;
        int e = rs + team;
        for (; e + 6 < re; e += 8) {   // edges e, e+2, e+4, e+6 (this team)
            int s0 = ssrc[e], s1 = ssrc[e + 2], s2 = ssrc[e + 4], s3 = ssrc[e + 6];
            half8 v0 = *(const half8*)&xin[(size_t)s0 * NHID + q16 * 8];
            half8 v1 = *(const half8*)&xin[(size_t)s1 * NHID + q16 * 8];
            half8 v2 = *(const half8*)&xin[(size_t)s2 * NHID + q16 * 8];
            half8 v3 = *(const half8*)&xin[(size_t)s3 * NHID + q16 * 8];
#pragma unroll
            for (int c = 0; c < 8; c++)
                acc[c] += ((float)v0[c] + (float)v1[c]) + ((float)v2[c] + (float)v3[c]);
        }
        for (; e < re; e += 2) {
            half8 v = *(const half8*)&xin[(size_t)ssrc[e] * NHID + q16 * 8];
#pragma unroll
            for (int c = 0; c < 8; c++) acc[c] += (float)v[c];
        }
        // combine team partials (lane ^ 16 = other team, same node/q16)
#pragma unroll
        for (int c = 0; c < 8; c++) acc[c] += __shfl_xor(acc[c], 16);
        int deg = re - rs;
        float inv = (deg > 0) ? (1.0f / (float)deg) : 0.f;
        if (team == 0) {
            half8 av;
#pragma unroll
            for (int c = 0; c < 8; c++) av[c] = (_Float16)(acc[c] * inv);
            *(half8*)&sAX[i][q16 * 8] = av;
            *(half8*)&sAX[i][128 + q16 * 8] =
                *(const half8*)&xin[(size_t)node * NHID + q16 * 8];
        }
    }
    __syncthreads();

    // ---- MFMA GEMM: wave = ntile
    {
        int lane = tid & 63;
        int wave = tid >> 6;          // 0..7
        int l15 = lane & 15;
        int g = lane >> 4;
        const _Float16* wb = WT + (size_t)(wave * 16 + l15) * 256 + g * 8;
        f32x4 acc = (f32x4){0.f, 0.f, 0.f, 0.f};
#pragma unroll
        for (int kt = 0; kt < 8; kt++) {
            half8 af = *(const half8*)&sAX[l15][kt * 32 + g * 8];
            half8 bf = *(const half8*)(wb + kt * 32);
            acc = __builtin_amdgcn_mfma_f32_16x16x32_f16(af, bf, acc, 0, 0, 0);
        }
        int o = wave * 16 + l15;
        float scale = gam[o] * rsqrtf(var[o] + 1e-5f);
        float bias = bet[o];
        float mean = mu[o];
        float bb = bl[o];
#pragma unroll
        for (int r = 0; r < 4; r++) {
            float hv = acc[r] + bb;
            hv = (hv - mean) * scale + bias;
            hv = fmaxf(hv, 0.f);
            outp[(size_t)(node0 + g * 4 + r) * NHID + o] = (_Float16)hv;
        }
    }
}

// ---------------- MFMA edge classifier (r14 + T5 setprio around MFMA clusters) ----------------
// 256 threads (4 waves), 64 edges/tile, grid-stride, grid=512 (2 independent
// blocks/CU at unsynchronized phases). setprio(1) during MFMA clusters lets the
// CU scheduler favor the block in compute over the co-resident block staging.
__global__ __launch_bounds__(256, 1) void classifier_mfma(
    const _Float16* __restrict__ h2f, const int* __restrict__ src,
    const int* __restrict__ dst,
    const float* __restrict__ attr, const float* __restrict__ tab,
    const _Float16* __restrict__ W1T, const float* __restrict__ bc1,
    const _Float16* __restrict__ W2T, const float* __restrict__ bc2,
    const _Float16* __restrict__ W3T, const float* __restrict__ bc3,
    float* __restrict__ out, int E, int ntiles) {
    __shared__ _Float16 repr[EPB][RP];    // 37888 B
    __shared__ _Float16 z1s[EPB][Z1P];    // 17408 B
    _Float16* z2f = &repr[0][0];          // [EPB][Z2P] aliases repr

    int tid = threadIdx.x;
    int lane = tid & 63;
    int wave = tid >> 6;
    int l15 = lane & 15;
    int g = lane >> 4;

    // persistent B fragments: 2 ntiles x 9 kt
    half8 B1[2][9];
#pragma unroll
    for (int nn = 0; nn < 2; nn++) {
        const _Float16* wb = W1T + (size_t)((2 * wave + nn) * 16 + l15) * 288 + g * 8;
#pragma unroll
        for (int kt = 0; kt < 9; kt++) B1[nn][kt] = *(const half8*)(wb + kt * 32);
    }
    // row-indexed biases (out-channel = g*4+r)
    float4 bias1v[2];
#pragma unroll
    for (int nn = 0; nn < 2; nn++)
        bias1v[nn] = *(const float4*)&bc1[(2 * wave + nn) * 16 + g * 4];
    half8 B2[4];
    const _Float16* w2base = W2T + (size_t)(wave * 16 + l15) * 128 + g * 8;
#pragma unroll
    for (int kt = 0; kt < 4; kt++) B2[kt] = *(const half8*)(w2base + kt * 32);
    float4 bias2v = *(const float4*)&bc2[wave * 16 + g * 4];
    half8 B3[2];
#pragma unroll
    for (int kt = 0; kt < 2; kt++)
        B3[kt] = *(const half8*)(W3T + (size_t)l15 * 64 + kt * 32 + g * 8);
    float b3_0 = bc3[0], b3_1 = bc3[1], b3_2 = bc3[2];

    for (int t = blockIdx.x; t < ntiles; t += gridDim.x) {
        int e0 = t * EPB;
        { // ---- stage repr: 4 threads/edge, batched 16B loads
            int el = tid >> 2, p = tid & 3;
            int e = e0 + el; if (e >= E) e = E - 1;
            int s = src[e], d = dst[e];
            const half8* hs = (const half8*)(h2f + (size_t)s * NHID + p * 32);
            const half8* hd = (const half8*)(h2f + (size_t)d * NHID + p * 32);
            half8* r = (half8*)&repr[el][0];
#pragma unroll
            for (int j = 0; j < 4; j++) r[p * 4 + j] = hs[j];
#pragma unroll
            for (int j = 0; j < 4; j++) r[16 + p * 4 + j] = hd[j];
            const float* ssrcp = (p < 2) ? (attr + (size_t)e * 16 + p * 8)
                                         : (tab + (size_t)e * 16 + (p - 2) * 8);
            int doff = (p < 2) ? (32 + p) : (34 + (p - 2));
            float4 a = ((const float4*)ssrcp)[0], b = ((const float4*)ssrcp)[1];
            half8 v;
            v[0] = (_Float16)a.x; v[1] = (_Float16)a.y; v[2] = (_Float16)a.z; v[3] = (_Float16)a.w;
            v[4] = (_Float16)b.x; v[5] = (_Float16)b.y; v[6] = (_Float16)b.z; v[7] = (_Float16)b.w;
            r[doff] = v;
        }
        __syncthreads();

        // ---- GEMM1 (swapped): D[row=out][col=edge]; 4 atiles x 2 ntiles
        __builtin_amdgcn_s_setprio(1);
#pragma unroll
        for (int at = 0; at < 4; at++) {
            const _Float16* ab = &repr[at * 16 + l15][g * 8];
            f32x4 acc0 = (f32x4){bias1v[0].x, bias1v[0].y, bias1v[0].z, bias1v[0].w};
            f32x4 acc1 = (f32x4){bias1v[1].x, bias1v[1].y, bias1v[1].z, bias1v[1].w};
#pragma unroll
            for (int kt = 0; kt < 9; kt++) {
                half8 af = *(const half8*)(ab + kt * 32);
                acc0 = __builtin_amdgcn_mfma_f32_16x16x32_f16(B1[0][kt], af, acc0, 0, 0, 0);
                acc1 = __builtin_amdgcn_mfma_f32_16x16x32_f16(B1[1][kt], af, acc1, 0, 0, 0);
            }
            half4v p0, p1;
#pragma unroll
            for (int r = 0; r < 4; r++) {
                p0[r] = (_Float16)fmaxf(acc0[r], 0.f);
                p1[r] = (_Float16)fmaxf(acc1[r], 0.f);
            }
            *(half4v*)&z1s[at * 16 + l15][(2 * wave + 0) * 16 + g * 4] = p0;
            *(half4v*)&z1s[at * 16 + l15][(2 * wave + 1) * 16 + g * 4] = p1;
        }
        __builtin_amdgcn_s_setprio(0);
        __syncthreads();

        // ---- GEMM2 (swapped): 4 atiles x 1 ntile -> z2f (aliases repr)
        __builtin_amdgcn_s_setprio(1);
#pragma unroll
        for (int a = 0; a < 4; a++) {
            const _Float16* ab = &z1s[a * 16 + l15][g * 8];
            f32x4 acc2 = (f32x4){bias2v.x, bias2v.y, bias2v.z, bias2v.w};
#pragma unroll
            for (int kt = 0; kt < 4; kt++)
                acc2 = __builtin_amdgcn_mfma_f32_16x16x32_f16(B2[kt], *(const half8*)(ab + kt * 32),
                                                              acc2, 0, 0, 0);
            half4v p;
#pragma unroll
            for (int r = 0; r < 4; r++) p[r] = (_Float16)fmaxf(acc2[r], 0.f);
            *(half4v*)&z2f[(size_t)(a * 16 + l15) * Z2P + wave * 16 + g * 4] = p;
        }
        __builtin_amdgcn_s_setprio(0);
        __syncthreads();

        // ---- GEMM3 (swapped): wave handles atile=wave; g=0 lanes hold c=0..2
        {
            const _Float16* ab = z2f + (size_t)(wave * 16 + l15) * Z2P + g * 8;
            f32x4 acc3 = (f32x4){0.f, 0.f, 0.f, 0.f};
#pragma unroll
            for (int kt = 0; kt < 2; kt++)
                acc3 = __builtin_amdgcn_mfma_f32_16x16x32_f16(B3[kt], *(const half8*)(ab + kt * 32),
                                                              acc3, 0, 0, 0);
            if (g == 0) {
                int e = e0 + wave * 16 + l15;
                if (e < E) {
                    out[(size_t)e * 3 + 0] = acc3[0] + b3_0;
                    out[(size_t)e * 3 + 1] = acc3[1] + b3_1;
                    out[(size_t)e * 3 + 2] = acc3[2] + b3_2;
                }
            }
        }
        __syncthreads();   // protect repr/z2f before next tile's staging
    }
}

extern "C" void kernel_launch(void* const* d_in, const int* in_sizes, int n_in,
                              void* d_out, int out_size, void* d_ws, size_t ws_size,
                              hipStream_t stream) {
    const float* x    = (const float*)d_in[0];
    const int*   ei   = (const int*)d_in[1];
    const float* attr = (const float*)d_in[2];
    const float* tab  = (const float*)d_in[3];
    const float* W1l  = (const float*)d_in[4];
    const float* b1l  = (const float*)d_in[5];
    const float* W1r  = (const float*)d_in[6];
    const float* W2l  = (const float*)d_in[7];
    const float* b2l  = (const float*)d_in[8];
    const float* W2r  = (const float*)d_in[9];
    const float* g1   = (const float*)d_in[10];
    const float* be1  = (const float*)d_in[11];
    const float* m1   = (const float*)d_in[12];
    const float* v1   = (const float*)d_in[13];
    const float* g2   = (const float*)d_in[14];
    const float* be2  = (const float*)d_in[15];
    const float* m2   = (const float*)d_in[16];
    const float* v2   = (const float*)d_in[17];
    const float* Wc1  = (const float*)d_in[18];
    const float* bc1  = (const float*)d_in[19];
    const float* Wc2  = (const float*)d_in[20];
    const float* bc2  = (const float*)d_in[21];
    const float* Wc3  = (const float*)d_in[22];
    const float* bc3  = (const float*)d_in[23];
    float* out = (float*)d_out;

    const int N = in_sizes[0] / NHID;     // 50000
    const int E = in_sizes[1] / 2;        // 800000

    // workspace layout (bytes)
    char* ws = (char*)d_ws;
    int*       rowptr = (int*)(ws + 0);                 // N+1 ints
    int*       cursor = (int*)(ws + 204800);            // N ints
    int*       deg    = (int*)(ws + 409600);            // N ints
    int*       ssrc   = (int*)(ws + 614400);            // E ints
    int*       bsum   = (int*)(ws + 3814400);
    int*       bpre   = (int*)(ws + 3815424);
    _Float16*  W1T    = (_Float16*)(ws + 3816448);      // 128x288
    _Float16*  W2T    = (_Float16*)(ws + 3890176);      // 64x128
    _Float16*  W3T    = (_Float16*)(ws + 3906560);      // 16x64
    _Float16*  WT1    = (_Float16*)(ws + 3908608);      // 128x256
    _Float16*  WT2    = (_Float16*)(ws + 3974144);      // 128x256
    _Float16*  xf     = (_Float16*)(ws + 4039680);      // N*128 f16
    _Float16*  h1f    = (_Float16*)(ws + 4039680 + (size_t)N * NHID * 2);
    _Float16*  h2f    = (_Float16*)(ws + 4039680 + 2 * (size_t)N * NHID * 2);

    const int* src = ei;
    const int* dst = ei + E;

    int eblocks = (E + 255) / 256;
    int cblocks = (N + 255) / 256;        // 196
    int nblocks16 = (N + 15) / 16;        // 3125
    int ntiles  = (E + EPB - 1) / EPB;    // 12500
    int cgrid   = 512;                    // exactly 2 blocks/CU resident
    if (cgrid > ntiles) cgrid = ntiles;
    int n8      = N * NHID / 8;           // 800000

    // 0) prep weights (f16, transposed) + f16 cast of x
    prep_weights<<<144, 256, 0, stream>>>(Wc1, Wc2, Wc3, W1l, W1r, W2l, W2r,
                                          W1T, W2T, W3T, WT1, WT2);
    cast_f32_f16<<<1024, 256, 0, stream>>>(x, xf, n8);
    // 1) CSR build
    zero_kernel<<<16, 256, 0, stream>>>((float*)deg, 204800 / 16);
    count_kernel<<<eblocks, 256, 0, stream>>>(dst, deg, E);
    csr_reduce<<<cblocks, 256, 0, stream>>>(deg, bsum, N);
    csr_scan_partials<<<1, 256, 0, stream>>>(bsum, bpre, rowptr, cblocks, N);
    csr_emit<<<cblocks, 256, 0, stream>>>(deg, bpre, rowptr, cursor, N);
    fill_kernel<<<eblocks, 256, 0, stream>>>(src, dst, cursor, ssrc, E);
    // 2) layer 1 -> h1f (f16)
    sage_layer<<<nblocks16, 512, 0, stream>>>(xf, rowptr, ssrc, WT1, b1l,
                                              g1, be1, m1, v1, h1f, N);
    // 3) layer 2 -> h2f (f16)
    sage_layer<<<nblocks16, 512, 0, stream>>>(h1f, rowptr, ssrc, WT2, b2l,
                                              g2, be2, m2, v2, h2f, N);
    // 4) MFMA edge classifier (r14 + setprio arbitration between co-resident blocks)
    classifier_mfma<<<cgrid, 256, 0, stream>>>(h2f, src, dst, attr, tab,
                                               W1T, bc1, W2T, bc2, W3T, bc3,
                                               out, E, ntiles);
}